// Round 7
// baseline (121.644 us; speedup 1.0000x reference)
//
#include <hip/hip_runtime.h>
#include <math.h>

#define BB 32
#define TT 2048
#define DD 64
#define PRED 96
#define TP (TT + PRED)      // 2144
#define KTOP 8
#define NSIG (BB * DD)      // 2048
#define MARGIN 8e-4f
#define PI_D 3.14159265358979323846

// bit-reversal tables
__device__ __forceinline__ int br6(int l) { return (int)(__brev((unsigned)l) >> 26); }
static constexpr int BR5[32] = {0,16,8,24,4,20,12,28,2,18,10,26,6,22,14,30,
                                1,17,9,25,5,21,13,29,3,19,11,27,7,23,15,31};
// cos/sin(2*pi*j/32), j=0..15 (compile-time twiddles for the in-lane FFT-32)
static constexpr float C32T[16] = {
    1.0f, 0.98078528040323044913f, 0.92387953251128675613f, 0.83146961230254523708f,
    0.70710678118654752440f, 0.55557023301960222474f, 0.38268343236508977173f, 0.19509032201612826785f,
    0.0f, -0.19509032201612826785f, -0.38268343236508977173f, -0.55557023301960222474f,
    -0.70710678118654752440f, -0.83146961230254523708f, -0.92387953251128675613f, -0.98078528040323044913f};
static constexpr float S32T[16] = {
    0.0f, 0.19509032201612826785f, 0.38268343236508977173f, 0.55557023301960222474f,
    0.70710678118654752440f, 0.83146961230254523708f, 0.92387953251128675613f, 0.98078528040323044913f,
    1.0f, 0.98078528040323044913f, 0.92387953251128675613f, 0.83146961230254523708f,
    0.70710678118654752440f, 0.55557023301960222474f, 0.38268343236508977173f, 0.19509032201612826785f};

// * exp(-2*pi*i*m/2048) via 1-ulp HW trig (revolutions input, exact dyadic)
__device__ __forceinline__ float2 ctw(float2 a, int m) {
    const float rev = (float)m * (1.0f / 2048.0f);
    const float c = __builtin_amdgcn_cosf(rev);
    const float s = __builtin_amdgcn_sinf(rev);
    return make_float2(a.x * c + a.y * s, a.y * c - a.x * s);
}

// ---------------------------------------------------------------------------
// Wave-autonomous kernel: one wave = one packed signal-pair (2 real channels
// as re/im of one complex 2048-pt FFT). FFT2048 = FFT32(in-lane, registers)
// x twiddle x FFT64(cross-lane via shfl_xor). No LDS exchanges, 1 barrier.
// Selection: u32-key bitonic top-16 (R6-proven). Ambiguity band around m8
// -> wave-local exact fp64 DFT of band members only.
// ---------------------------------------------------------------------------
__global__ __launch_bounds__(256) void fft_topk_kernel(const float* __restrict__ x,
                                                       int* __restrict__ idxw,
                                                       float* __restrict__ rew,
                                                       float* __restrict__ imw) {
    __shared__ float SRe[4][2112];                 // skewed spectrum a(k)=k+(k>>5)
    __shared__ float SIm[4][2112];                 // 67.6 KB total

    const int t    = threadIdx.x;
    const int wv   = t >> 6, lane = t & 63;
    // XCD swizzle: 8 blocks of one batch b land on one XCD.
    const int bid  = blockIdx.x;
    const int xcd  = bid & 7;
    const int idx  = bid >> 3;                     // 0..31
    const int b    = xcd * 4 + (idx >> 3);         // 0..31
    const int dp   = (idx & 7) * 4 + wv;           // d-pair 0..31

    const float2* xv = (const float2*)x;
    const size_t xbase = (size_t)b * TT * (DD / 2) + dp;

    // ---- load: v[i] = x[n = 64*br5(i) + lane] (bit-reversed for DIT-32) ----
    float2 v[32];
    #pragma unroll
    for (int i = 0; i < 32; ++i)
        v[i] = xv[xbase + (size_t)(64 * BR5[i] + lane) * (DD / 2)];

    // ---- in-lane FFT-32 (DIT, natural-order output, constant twiddles) ----
    #pragma unroll
    for (int s = 1; s <= 5; ++s) {
        const int m = 1 << s, half = m >> 1, stepw = 32 >> s;
        #pragma unroll
        for (int g = 0; g < 32; g += m) {
            #pragma unroll
            for (int j = 0; j < half; ++j) {
                const float c = C32T[j * stepw], sn = S32T[j * stepw];
                const int i0 = g + j, i1 = i0 + half;
                const float tr = c * v[i1].x + sn * v[i1].y;
                const float ti = c * v[i1].y - sn * v[i1].x;
                v[i1] = make_float2(v[i0].x - tr, v[i0].y - ti);
                v[i0] = make_float2(v[i0].x + tr, v[i0].y + ti);
            }
        }
    }

    // ---- twiddle: v[q] *= W2048^(lane*q) ----
    #pragma unroll
    for (int q = 1; q < 32; ++q) v[q] = ctw(v[q], (lane * q) & (TT - 1));

    // ---- cross-lane FFT-64: bit-reverse lanes, then 6 DIT shuffle stages ----
    {
        const int rl = br6(lane);
        #pragma unroll
        for (int q = 0; q < 32; ++q) {
            v[q].x = __shfl(v[q].x, rl, 64);
            v[q].y = __shfl(v[q].y, rl, 64);
        }
    }
    #pragma unroll
    for (int s = 1; s <= 6; ++s) {
        const int half = 1 << (s - 1);
        const float rev = (float)(lane & (half - 1)) / (float)(1 << s);
        const float wc  = __builtin_amdgcn_cosf(rev);
        const float wsn = __builtin_amdgcn_sinf(rev);
        const bool  hi  = (lane & half) != 0;
        #pragma unroll
        for (int q = 0; q < 32; ++q) {
            float2 pv;
            pv.x = __shfl_xor(v[q].x, half, 64);
            pv.y = __shfl_xor(v[q].y, half, 64);
            const float2 bsv = hi ? v[q] : pv;     // B operand
            const float2 asv = hi ? pv : v[q];     // A operand
            const float tr = wc * bsv.x + wsn * bsv.y;
            const float ti = wc * bsv.y - wsn * bsv.x;
            v[q] = hi ? make_float2(asv.x - tr, asv.y - ti)
                      : make_float2(asv.x + tr, asv.y + ti);
        }
    }
    // lane c now holds X[32c + q] in v[q], natural order.

    // ---- dump spectrum (skewed: bank = (lane+q)&31, conflict-free) ----
    #pragma unroll
    for (int q = 0; q < 32; ++q) {
        const int k = 32 * lane + q;
        const int a = k + (k >> 5);                // = 33*lane + q
        SRe[wv][a] = v[q].x;
        SIm[wv][a] = v[q].y;
    }
    __syncthreads();                               // the only barrier

    const int s_base = b * DD + 2 * dp;

    int   flgv[2]  = {0, 0};
    int   kwinv[2] = {0, 0};                       // lanes<16: cand k per sig
    unsigned bandmaskv[2] = {0, 0};

    #pragma unroll
    for (int sig = 0; sig < 2; ++sig) {
        // ---- keys: lanes<32 own bins k = 32*lane + q (k=0 excluded) ----
        unsigned key[32];
        if (lane < 32) {
            #pragma unroll
            for (int q = 0; q < 32; ++q) {
                const int k = 32 * lane + q;
                unsigned kk = 0u;
                if (k != 0) {
                    const int pk = TT - k, a2 = pk + (pk >> 5);
                    const float yr = SRe[wv][a2], yi = SIm[wv][a2];
                    const float zr = v[q].x, zi = v[q].y;
                    float cr, ci;
                    if (sig == 0) { cr = 0.5f * (zr + yr); ci = 0.5f * (zi - yi); }
                    else          { cr = 0.5f * (zi + yi); ci = 0.5f * (yr - zr); }
                    const float mg = cr * cr + ci * ci;
                    kk = (__float_as_uint(mg) & 0xFFFFF800u) | (unsigned)(2047 - k);
                }
                key[q] = kk;
            }
        } else {
            #pragma unroll
            for (int q = 0; q < 32; ++q) key[q] = 0u;
        }

        // redistribute 32keys/lane(lo half) -> 16 keys on all 64 lanes
        unsigned A[16];
        #pragma unroll
        for (int j = 0; j < 16; ++j) {
            const unsigned u = (unsigned)__shfl((int)key[j + 16], lane & 31, 64);
            A[j] = (lane < 32) ? key[j] : u;
        }

        // in-register bitonic sort-16, descending
        #pragma unroll
        for (int sz = 2; sz <= 16; sz <<= 1) {
            #pragma unroll
            for (int d = sz >> 1; d > 0; d >>= 1) {
                #pragma unroll
                for (int i2 = 0; i2 < 16; ++i2) {
                    const int j2i = i2 ^ d;
                    if (j2i > i2) {
                        const bool desc = ((i2 & sz) == 0);
                        const unsigned a = A[i2], b2 = A[j2i];
                        const unsigned mx = a > b2 ? a : b2, mn = a > b2 ? b2 : a;
                        A[i2] = desc ? mx : mn;  A[j2i] = desc ? mn : mx;
                    }
                }
            }
        }
        // 6 XOR-merge stages (pipelined shuffles + max-trick + half-clean)
        #pragma unroll
        for (int off = 1; off < 64; off <<= 1) {
            unsigned Bv[16];
            #pragma unroll
            for (int i2 = 0; i2 < 16; ++i2)
                Bv[i2] = (unsigned)__shfl_xor((int)A[i2], off, 64);
            #pragma unroll
            for (int i2 = 0; i2 < 16; ++i2) {
                const unsigned o = Bv[15 - i2];
                A[i2] = A[i2] > o ? A[i2] : o;
            }
            #pragma unroll
            for (int d = 8; d > 0; d >>= 1) {
                #pragma unroll
                for (int i2 = 0; i2 < 16; ++i2) {
                    if ((i2 & d) == 0) {
                        const int j2i = i2 + d;
                        const unsigned a = A[i2], b2 = A[j2i];
                        A[i2] = a > b2 ? a : b2;  A[j2i] = a > b2 ? b2 : a;
                    }
                }
            }
        }
        // every lane: global top-16, descending

        // ambiguity band around m8 (set-membership boundary)
        const float m8f = __uint_as_float(A[7] & 0xFFFFF800u);
        unsigned bandmask = 0u;
        #pragma unroll
        for (int r = 0; r < 16; ++r) {
            const float mr = __uint_as_float(A[r] & 0xFFFFF800u);
            if (fabsf(mr - m8f) <= MARGIN * m8f) bandmask |= (1u << r);
        }
        const int flg = (bandmask != (1u << 7));
        flgv[sig] = flg; bandmaskv[sig] = bandmask;

        unsigned myk = 0u;
        #pragma unroll
        for (int i2 = 0; i2 < 16; ++i2) myk = (lane == i2) ? A[i2] : myk;
        const int kwin = 2047 - (int)(myk & 0x7FFu);
        kwinv[sig] = kwin;

        if (!flg && lane < KTOP) {
            const int k = kwin, a1 = k + (k >> 5), pk = TT - k, a2 = pk + (pk >> 5);
            const float zr = SRe[wv][a1], zi = SIm[wv][a1];
            const float yr = SRe[wv][a2], yi = SIm[wv][a2];
            float cr, ci;
            if (sig == 0) { cr = 0.5f * (zr + yr); ci = 0.5f * (zi - yi); }
            else          { cr = 0.5f * (zi + yi); ci = 0.5f * (yr - zr); }
            const int s_sig = s_base + sig;
            idxw[s_sig * KTOP + lane] = k;
            rew[s_sig * KTOP + lane]  = cr * (2.0f / (float)TT);
            imw[s_sig * KTOP + lane]  = ci * (2.0f / (float)TT);
        }
    }

    // ---- rare path: fp64 DFT of band members, exact re-rank + splice ----
    if (flgv[0] | flgv[1]) {
        float2 sv[32];
        #pragma unroll
        for (int m = 0; m < 32; ++m)
            sv[m] = xv[xbase + (size_t)(lane + 64 * m) * (DD / 2)];
        // lane-register twiddle tables: WA[l]=exp(-2pi*i*l/64), WB[l]=exp(-2pi*i*l/2048)
        const double thA = -2.0 * PI_D * (double)lane / 64.0;
        const double thB = -2.0 * PI_D * (double)lane / (double)TT;
        const double wac = cos(thA), was = sin(thA);
        const double wbc = cos(thB), wbs = sin(thB);

        for (int sig = 0; sig < 2; ++sig) {
            if (!flgv[sig]) continue;
            const unsigned bandmask = bandmaskv[sig];
            const int lo = (int)__builtin_ctz(bandmask);
            double myM = 0.0, myR = 0.0, myI = 0.0;
            for (int r = 0; r < 16; ++r) {
                if (!((bandmask >> r) & 1u)) continue;      // wave-uniform
                const int kr = __shfl(kwinv[sig], r, 64);
                double ar = 0.0, ai = 0.0;
                for (int m = 0; m < 32; ++m) {
                    const int n  = lane + 64 * m;
                    const int mm = (n * kr) & (TT - 1);
                    const double qc = __shfl(wac, mm >> 5, 64);
                    const double qs = __shfl(was, mm >> 5, 64);
                    const double rc = __shfl(wbc, mm & 31, 64);
                    const double rs = __shfl(wbs, mm & 31, 64);
                    const double wr = qc * rc - qs * rs;
                    const double wi = qc * rs + qs * rc;
                    const double xs = (sig == 0) ? (double)sv[m].x : (double)sv[m].y;
                    ar = fma(xs, wr, ar);
                    ai = fma(xs, wi, ai);
                }
                #pragma unroll
                for (int off = 32; off; off >>= 1) {
                    ar += __shfl_xor(ar, off, 64);
                    ai += __shfl_xor(ai, off, 64);
                }
                if (lane == r) { myM = ar * ar + ai * ai; myR = ar; myI = ai; }
            }
            // rank: band members re-ranked by fp64 (tie -> low k); others keep slot
            int rank = lane;
            if (lane < 16 && ((bandmask >> lane) & 1u)) {
                int rb = 0;
                for (int r2 = 0; r2 < 16; ++r2) {
                    if (!((bandmask >> r2) & 1u)) continue;
                    const double om = __shfl(myM, r2, 64);
                    const int    ok = __shfl(kwinv[sig], r2, 64);
                    if (r2 != lane &&
                        (om > myM || (om == myM && ok < kwinv[sig]))) ++rb;
                }
                rank = lo + rb;
            }
            if (lane < 16 && rank < KTOP) {
                const int s_sig = s_base + sig;
                const int k = kwinv[sig];
                idxw[s_sig * KTOP + rank] = k;
                if ((bandmask >> lane) & 1u) {
                    rew[s_sig * KTOP + rank] = (float)(myR * (2.0 / (double)TT));
                    imw[s_sig * KTOP + rank] = (float)(myI * (2.0 / (double)TT));
                } else {
                    const int a1 = k + (k >> 5), pk = TT - k, a2 = pk + (pk >> 5);
                    const float zr = SRe[wv][a1], zi = SIm[wv][a1];
                    const float yr = SRe[wv][a2], yi = SIm[wv][a2];
                    float cr, ci;
                    if (sig == 0) { cr = 0.5f * (zr + yr); ci = 0.5f * (zi - yi); }
                    else          { cr = 0.5f * (zi + yi); ci = 0.5f * (yr - zr); }
                    rew[s_sig * KTOP + rank] = cr * (2.0f / (float)TT);
                    imw[s_sig * KTOP + rank] = ci * (2.0f / (float)TT);
                }
            }
        }
    }
}

// ---------------------------------------------------------------------------
// Synthesis (verified): d-major lanes, coalesced stores, exact integer angle
// reduction + HW trig.
// ---------------------------------------------------------------------------
__global__ __launch_bounds__(256) void synth_kernel(const int* __restrict__ idxw,
                                                    const float* __restrict__ rew,
                                                    const float* __restrict__ imw,
                                                    float* __restrict__ out) {
    const int NT   = (TP + 127) / 128;   // 17 tiles
    const int b    = blockIdx.x / NT;
    const int tile = blockIdx.x % NT;
    const int tid  = threadIdx.x;
    const int d    = tid & 63;
    const int tq   = tid >> 6;
    const int s    = b * DD + d;

    int   kk[KTOP];
    float rr[KTOP], ii[KTOP];
    int   jj[KTOP];
    #pragma unroll
    for (int p = 0; p < KTOP; ++p) {
        kk[p] = idxw[s * KTOP + p];
        rr[p] = rew[s * KTOP + p];
        ii[p] = imw[s * KTOP + p];
    }
    const int t0 = tile * 128 + tq * 32;
    #pragma unroll
    for (int p = 0; p < KTOP; ++p) jj[p] = (kk[p] * t0) & (TT - 1);

    const float invT = 1.0f / (float)TT;
    for (int i = 0; i < 32; ++i) {
        const int t = t0 + i;
        if (t < TP) {
            float acc = 0.0f;
            #pragma unroll
            for (int p = 0; p < KTOP; ++p) {
                const float rev = (float)jj[p] * invT;
                const float c  = __builtin_amdgcn_cosf(rev);
                const float sn = __builtin_amdgcn_sinf(rev);
                acc += rr[p] * c - ii[p] * sn;
            }
            out[((size_t)b * TP + t) * DD + d] = acc;
        }
        #pragma unroll
        for (int p = 0; p < KTOP; ++p) jj[p] = (jj[p] + kk[p]) & (TT - 1);
    }
}

extern "C" void kernel_launch(void* const* d_in, const int* in_sizes, int n_in,
                              void* d_out, int out_size, void* d_ws, size_t ws_size,
                              hipStream_t stream) {
    const float* x = (const float*)d_in[0];
    float* out = (float*)d_out;

    char* p = (char*)d_ws;
    int*   idxw = (int*)p;     p += (size_t)NSIG * KTOP * sizeof(int);
    float* rew  = (float*)p;   p += (size_t)NSIG * KTOP * sizeof(float);
    float* imw  = (float*)p;

    fft_topk_kernel<<<NSIG / 8, 256, 0, stream>>>(x, idxw, rew, imw);

    const int NT = (TP + 127) / 128;
    synth_kernel<<<BB * NT, 256, 0, stream>>>(idxw, rew, imw, out);
}

// Round 8
// 112.647 us; speedup vs baseline: 1.0799x; 1.0799x over previous
//
#include <hip/hip_runtime.h>
#include <math.h>

#define BB 32
#define TT 2048
#define DD 64
#define PRED 96
#define TP (TT + PRED)      // 2144
#define KTOP 8
#define MARGIN 8e-4f
#define PI_D 3.14159265358979323846

// bit-reversal tables
__device__ __forceinline__ int br6(int l) { return (int)(__brev((unsigned)l) >> 26); }
static constexpr int BR5[32] = {0,16,8,24,4,20,12,28,2,18,10,26,6,22,14,30,
                                1,17,9,25,5,21,13,29,3,19,11,27,7,23,15,31};
// cos/sin(2*pi*j/32), j=0..15 (compile-time twiddles for the in-lane FFT-32)
static constexpr float C32T[16] = {
    1.0f, 0.98078528040323044913f, 0.92387953251128675613f, 0.83146961230254523708f,
    0.70710678118654752440f, 0.55557023301960222474f, 0.38268343236508977173f, 0.19509032201612826785f,
    0.0f, -0.19509032201612826785f, -0.38268343236508977173f, -0.55557023301960222474f,
    -0.70710678118654752440f, -0.83146961230254523708f, -0.92387953251128675613f, -0.98078528040323044913f};
static constexpr float S32T[16] = {
    0.0f, 0.19509032201612826785f, 0.38268343236508977173f, 0.55557023301960222474f,
    0.70710678118654752440f, 0.83146961230254523708f, 0.92387953251128675613f, 0.98078528040323044913f,
    1.0f, 0.98078528040323044913f, 0.92387953251128675613f, 0.83146961230254523708f,
    0.70710678118654752440f, 0.55557023301960222474f, 0.38268343236508977173f, 0.19509032201612826785f};

// * exp(-2*pi*i*m/2048) via 1-ulp HW trig (revolutions input, exact dyadic)
__device__ __forceinline__ float2 ctw(float2 a, int m) {
    const float rev = (float)m * (1.0f / 2048.0f);
    const float c = __builtin_amdgcn_cosf(rev);
    const float s = __builtin_amdgcn_sinf(rev);
    return make_float2(a.x * c + a.y * s, a.y * c - a.x * s);
}

// ---------------------------------------------------------------------------
// Single fused kernel. 256 blocks x 256 threads. One wave = one packed
// signal-pair (FFT2048 = in-lane FFT32 x twiddle x cross-lane FFT64, R7-
// verified). Selection: both channels in ONE pass (half-wave per channel,
// sort-32 + 5 XOR-merge stages). Rare fp64 refine for margin-flagged
// channels. Coefficients pass through LDS; block then synthesizes its own
// 8 d-channels with phasor-rotation (4 fma/term instead of 2 trig).
// ---------------------------------------------------------------------------
__global__ __launch_bounds__(256) void fused_kernel(const float* __restrict__ x,
                                                    float* __restrict__ out) {
    __shared__ float SRe[4][2112];                 // skewed spectrum a(k)=k+(k>>5)
    __shared__ float SIm[4][2112];                 // 67.6 KB
    __shared__ int   coefK[8][KTOP];
    __shared__ float coefR[8][KTOP], coefI[8][KTOP];

    const int t    = threadIdx.x;
    const int wv   = t >> 6, lane = t & 63;
    // XCD swizzle: 8 blocks of one batch b land on one XCD.
    const int bid  = blockIdx.x;
    const int xcd  = bid & 7;
    const int idx  = bid >> 3;                     // 0..31
    const int b    = xcd * 4 + (idx >> 3);         // 0..31
    const int grp  = idx & 7;                      // d-group 0..7
    const int dp   = grp * 4 + wv;                 // d-pair 0..31
    const int d_base = grp * 8;

    const float2* xv = (const float2*)x;
    const size_t xbase = (size_t)b * TT * (DD / 2) + dp;

    // ---- load: v[i] = x[n = 64*br5(i) + lane] (bit-reversed for DIT-32) ----
    float2 v[32];
    #pragma unroll
    for (int i = 0; i < 32; ++i)
        v[i] = xv[xbase + (size_t)(64 * BR5[i] + lane) * (DD / 2)];

    // ---- in-lane FFT-32 (DIT, natural-order output, constant twiddles) ----
    #pragma unroll
    for (int s = 1; s <= 5; ++s) {
        const int m = 1 << s, half = m >> 1, stepw = 32 >> s;
        #pragma unroll
        for (int g = 0; g < 32; g += m) {
            #pragma unroll
            for (int j = 0; j < half; ++j) {
                const float c = C32T[j * stepw], sn = S32T[j * stepw];
                const int i0 = g + j, i1 = i0 + half;
                const float tr = c * v[i1].x + sn * v[i1].y;
                const float ti = c * v[i1].y - sn * v[i1].x;
                v[i1] = make_float2(v[i0].x - tr, v[i0].y - ti);
                v[i0] = make_float2(v[i0].x + tr, v[i0].y + ti);
            }
        }
    }

    // ---- twiddle: v[q] *= W2048^(lane*q) ----
    #pragma unroll
    for (int q = 1; q < 32; ++q) v[q] = ctw(v[q], (lane * q) & (TT - 1));

    // ---- cross-lane FFT-64: bit-reverse lanes, then 6 DIT shuffle stages ----
    {
        const int rl = br6(lane);
        #pragma unroll
        for (int q = 0; q < 32; ++q) {
            v[q].x = __shfl(v[q].x, rl, 64);
            v[q].y = __shfl(v[q].y, rl, 64);
        }
    }
    #pragma unroll
    for (int s = 1; s <= 6; ++s) {
        const int half = 1 << (s - 1);
        const float rev = (float)(lane & (half - 1)) / (float)(1 << s);
        const float wc  = __builtin_amdgcn_cosf(rev);
        const float wsn = __builtin_amdgcn_sinf(rev);
        const bool  hi  = (lane & half) != 0;
        #pragma unroll
        for (int q = 0; q < 32; ++q) {
            float2 pv;
            pv.x = __shfl_xor(v[q].x, half, 64);
            pv.y = __shfl_xor(v[q].y, half, 64);
            const float2 bsv = hi ? v[q] : pv;
            const float2 asv = hi ? pv : v[q];
            const float tr = wc * bsv.x + wsn * bsv.y;
            const float ti = wc * bsv.y - wsn * bsv.x;
            v[q] = hi ? make_float2(asv.x - tr, asv.y - ti)
                      : make_float2(asv.x + tr, asv.y + ti);
        }
    }
    // lane c holds X[32c + q] in v[q].

    // ---- dump spectrum (skewed, conflict-free) ----
    #pragma unroll
    for (int q = 0; q < 32; ++q) {
        const int a = 33 * lane + q;               // k=32*lane+q, a=k+(k>>5)
        SRe[wv][a] = v[q].x;
        SIm[wv][a] = v[q].y;
    }
    __syncthreads();                               // barrier 1 of 2

    // ======== selection: BOTH channels in one pass ========
    // lanes 0-31 -> sig0 (.x), lanes 32-63 -> sig1 (.y). Each half-wave:
    // 32 keys/lane covering bins 32*hl .. 32*hl+31, sort-32 + 5 merges.
    const int sig = lane >> 5, hl = lane & 31;
    unsigned A[32];
    #pragma unroll
    for (int q = 0; q < 32; ++q) {
        const int k = 32 * hl + q;
        unsigned kk = 0u;
        if (k != 0) {
            const int a1 = k + (k >> 5);
            const int pk = TT - k, a2 = pk + (pk >> 5);
            const float zr = SRe[wv][a1], zi = SIm[wv][a1];
            const float yr = SRe[wv][a2], yi = SIm[wv][a2];
            float cr, ci;
            if (sig == 0) { cr = 0.5f * (zr + yr); ci = 0.5f * (zi - yi); }
            else          { cr = 0.5f * (zi + yi); ci = 0.5f * (yr - zr); }
            const float mg = cr * cr + ci * ci;
            kk = (__float_as_uint(mg) & 0xFFFFF800u) | (unsigned)(2047 - k);
        }
        A[q] = kk;
    }

    // in-register bitonic sort-32, descending
    #pragma unroll
    for (int sz = 2; sz <= 32; sz <<= 1) {
        #pragma unroll
        for (int d = sz >> 1; d > 0; d >>= 1) {
            #pragma unroll
            for (int i2 = 0; i2 < 32; ++i2) {
                const int j2i = i2 ^ d;
                if (j2i > i2) {
                    const bool desc = ((i2 & sz) == 0);
                    const unsigned a = A[i2], b2 = A[j2i];
                    const unsigned mx = a > b2 ? a : b2, mn = a > b2 ? b2 : a;
                    A[i2] = desc ? mx : mn;  A[j2i] = desc ? mn : mx;
                }
            }
        }
    }
    // 5 XOR-merge stages within each 32-lane half (off < 32 stays in half)
    #pragma unroll
    for (int off = 1; off <= 16; off <<= 1) {
        unsigned Bv[32];
        #pragma unroll
        for (int i2 = 0; i2 < 32; ++i2)
            Bv[i2] = (unsigned)__shfl_xor((int)A[i2], off, 64);
        #pragma unroll
        for (int i2 = 0; i2 < 32; ++i2) {
            const unsigned o = Bv[31 - i2];
            A[i2] = A[i2] > o ? A[i2] : o;         // top-32 multiset, bitonic
        }
        #pragma unroll
        for (int d = 16; d > 0; d >>= 1) {
            #pragma unroll
            for (int i2 = 0; i2 < 32; ++i2) {
                if ((i2 & d) == 0) {
                    const int j2i = i2 + d;
                    const unsigned a = A[i2], b2 = A[j2i];
                    A[i2] = a > b2 ? a : b2;  A[j2i] = a > b2 ? b2 : a;
                }
            }
        }
    }
    // every lane of half s: sorted top-32 of channel s (we use top-16)

    const float m8f = __uint_as_float(A[7] & 0xFFFFF800u);
    unsigned bandmask = 0u;
    #pragma unroll
    for (int r = 0; r < 16; ++r) {
        const float mr = __uint_as_float(A[r] & 0xFFFFF800u);
        if (fabsf(mr - m8f) <= MARGIN * m8f) bandmask |= (1u << r);
    }
    const int flg = (bandmask != (1u << 7)) ? 1 : 0;   // uniform per half

    unsigned myk = 0u;                                 // cand hl (hl<16)
    #pragma unroll
    for (int i2 = 0; i2 < 16; ++i2) myk = (hl == i2) ? A[i2] : myk;
    const int kcand = 2047 - (int)(myk & 0x7FFu);
    const int s_local = 2 * wv + sig;                  // block-local signal 0..7

    if (!flg && hl < KTOP) {
        const int k = kcand, a1 = k + (k >> 5), pk = TT - k, a2 = pk + (pk >> 5);
        const float zr = SRe[wv][a1], zi = SIm[wv][a1];
        const float yr = SRe[wv][a2], yi = SIm[wv][a2];
        float cr, ci;
        if (sig == 0) { cr = 0.5f * (zr + yr); ci = 0.5f * (zi - yi); }
        else          { cr = 0.5f * (zi + yi); ci = 0.5f * (yr - zr); }
        coefK[s_local][hl] = k;
        coefR[s_local][hl] = cr * (2.0f / (float)TT);
        coefI[s_local][hl] = ci * (2.0f / (float)TT);
    }

    const int flg0 = __shfl(flg, 0, 64);
    const int flg1 = __shfl(flg, 32, 64);

    // ---- rare path: fp64 DFT of band members, exact re-rank + splice ----
    if (flg0 | flg1) {
        float2 sv[32];
        #pragma unroll
        for (int m = 0; m < 32; ++m)
            sv[m] = xv[xbase + (size_t)(lane + 64 * m) * (DD / 2)];
        const double thA = -2.0 * PI_D * (double)lane / 64.0;
        const double thB = -2.0 * PI_D * (double)lane / (double)TT;
        const double wac = cos(thA), was = sin(thA);
        const double wbc = cos(thB), wbs = sin(thB);

        for (int sg = 0; sg < 2; ++sg) {
            const int flg_s = (sg == 0) ? flg0 : flg1;
            if (!flg_s) continue;
            const unsigned bm = (unsigned)__shfl((int)bandmask, 32 * sg, 64);
            const int lo = (int)__builtin_ctz(bm);
            double myM = 0.0, myR = 0.0, myI = 0.0;
            for (int r = 0; r < 16; ++r) {
                if (!((bm >> r) & 1u)) continue;       // wave-uniform
                const int kr = __shfl(kcand, 32 * sg + r, 64);
                double ar = 0.0, ai = 0.0;
                for (int m = 0; m < 32; ++m) {
                    const int n  = lane + 64 * m;
                    const int mm = (n * kr) & (TT - 1);
                    const double qc  = __shfl(wac, mm >> 5, 64);
                    const double qs  = __shfl(was, mm >> 5, 64);
                    const double rc2 = __shfl(wbc, mm & 31, 64);
                    const double rs2 = __shfl(wbs, mm & 31, 64);
                    const double wr = qc * rc2 - qs * rs2;
                    const double wi = qc * rs2 + qs * rc2;
                    const double xs = (sg == 0) ? (double)sv[m].x : (double)sv[m].y;
                    ar = fma(xs, wr, ar);
                    ai = fma(xs, wi, ai);
                }
                #pragma unroll
                for (int off = 32; off; off >>= 1) {
                    ar += __shfl_xor(ar, off, 64);
                    ai += __shfl_xor(ai, off, 64);
                }
                if (lane == 32 * sg + r) { myM = ar * ar + ai * ai; myR = ar; myI = ai; }
            }
            // rank on ALL lanes (shuffles fully active), write on half sg
            const int h16 = hl & 15;
            const double selfM = __shfl(myM, 32 * sg + h16, 64);
            const int    selfK = __shfl(kcand, 32 * sg + h16, 64);
            int rb = 0;
            for (int r2 = 0; r2 < 16; ++r2) {
                if (!((bm >> r2) & 1u)) continue;
                const double om = __shfl(myM, 32 * sg + r2, 64);
                const int    ok = __shfl(kcand, 32 * sg + r2, 64);
                if (r2 != h16 && (om > selfM || (om == selfM && ok < selfK))) ++rb;
            }
            const int isband = (int)((bm >> h16) & 1u);
            const int rank = isband ? (lo + rb) : h16;
            if (sig == sg && hl < 16 && rank < KTOP) {
                coefK[s_local][rank] = kcand;
                if (isband) {
                    coefR[s_local][rank] = (float)(myR * (2.0 / (double)TT));
                    coefI[s_local][rank] = (float)(myI * (2.0 / (double)TT));
                } else {
                    const int k = kcand, a1 = k + (k >> 5), pk = TT - k, a2 = pk + (pk >> 5);
                    const float zr = SRe[wv][a1], zi = SIm[wv][a1];
                    const float yr = SRe[wv][a2], yi = SIm[wv][a2];
                    float cr, ci;
                    if (sg == 0) { cr = 0.5f * (zr + yr); ci = 0.5f * (zi - yi); }
                    else          { cr = 0.5f * (zi + yi); ci = 0.5f * (yr - zr); }
                    coefR[s_local][rank] = cr * (2.0f / (float)TT);
                    coefI[s_local][rank] = ci * (2.0f / (float)TT);
                }
            }
        }
    }
    __syncthreads();                               // barrier 2 of 2

    // ======== synthesis (in-block, phasor rotation) ========
    // thread -> (d8 = t&7 local channel, tq = t>>3 base time); t = tq + 32m.
    const int d8 = t & 7, tq = t >> 3;
    int   kc[KTOP];
    float fr[KTOP], fi[KTOP], pc[KTOP], ps[KTOP], rc[KTOP], rs[KTOP];
    #pragma unroll
    for (int p = 0; p < KTOP; ++p) {
        kc[p] = coefK[d8][p];
        fr[p] = coefR[d8][p];
        fi[p] = coefI[d8][p];
        const int j0 = (kc[p] * tq) & (TT - 1);
        const float rv0 = (float)j0 * (1.0f / 2048.0f);
        pc[p] = __builtin_amdgcn_cosf(rv0);
        ps[p] = __builtin_amdgcn_sinf(rv0);
        const int jr = (kc[p] * 32) & (TT - 1);
        const float rvr = (float)jr * (1.0f / 2048.0f);
        rc[p] = __builtin_amdgcn_cosf(rvr);
        rs[p] = __builtin_amdgcn_sinf(rvr);
    }
    float* op = out + (size_t)b * TP * DD + d_base + d8;
    #pragma unroll 4
    for (int m = 0; m < 67; ++m) {                 // 67*32 = 2144 = TP exactly
        const int tv = tq + 32 * m;
        float acc = 0.0f;
        #pragma unroll
        for (int p = 0; p < KTOP; ++p) acc += fr[p] * pc[p] - fi[p] * ps[p];
        op[(size_t)tv * DD] = acc;
        #pragma unroll
        for (int p = 0; p < KTOP; ++p) {
            const float nc = pc[p] * rc[p] - ps[p] * rs[p];
            const float ns = pc[p] * rs[p] + ps[p] * rc[p];
            pc[p] = nc; ps[p] = ns;
        }
    }
}

extern "C" void kernel_launch(void* const* d_in, const int* in_sizes, int n_in,
                              void* d_out, int out_size, void* d_ws, size_t ws_size,
                              hipStream_t stream) {
    const float* x = (const float*)d_in[0];
    float* out = (float*)d_out;
    (void)d_ws; (void)ws_size; (void)in_sizes; (void)n_in; (void)out_size;

    fused_kernel<<<BB * 8, 256, 0, stream>>>(x, out);
}

// Round 9
// 110.934 us; speedup vs baseline: 1.0965x; 1.0154x over previous
//
#include <hip/hip_runtime.h>
#include <math.h>

#define BB 32
#define TT 2048
#define DD 64
#define PRED 96
#define TP (TT + PRED)      // 2144
#define KTOP 8
#define MARGIN 8e-4f
#define PI_D 3.14159265358979323846

// bit-reversal tables
__device__ __forceinline__ int br6(int l) { return (int)(__brev((unsigned)l) >> 26); }
static constexpr int BR5[32] = {0,16,8,24,4,20,12,28,2,18,10,26,6,22,14,30,
                                1,17,9,25,5,21,13,29,3,19,11,27,7,23,15,31};
// cos/sin(2*pi*j/32), j=0..15 (compile-time twiddles for the in-lane FFT-32)
static constexpr float C32T[16] = {
    1.0f, 0.98078528040323044913f, 0.92387953251128675613f, 0.83146961230254523708f,
    0.70710678118654752440f, 0.55557023301960222474f, 0.38268343236508977173f, 0.19509032201612826785f,
    0.0f, -0.19509032201612826785f, -0.38268343236508977173f, -0.55557023301960222474f,
    -0.70710678118654752440f, -0.83146961230254523708f, -0.92387953251128675613f, -0.98078528040323044913f};
static constexpr float S32T[16] = {
    0.0f, 0.19509032201612826785f, 0.38268343236508977173f, 0.55557023301960222474f,
    0.70710678118654752440f, 0.83146961230254523708f, 0.92387953251128675613f, 0.98078528040323044913f,
    1.0f, 0.98078528040323044913f, 0.92387953251128675613f, 0.83146961230254523708f,
    0.70710678118654752440f, 0.55557023301960222474f, 0.38268343236508977173f, 0.19509032201612826785f};

// * exp(-2*pi*i*m/2048) via 1-ulp HW trig (revolutions input, exact dyadic)
__device__ __forceinline__ float2 ctw(float2 a, int m) {
    const float rev = (float)m * (1.0f / 2048.0f);
    const float c = __builtin_amdgcn_cosf(rev);
    const float s = __builtin_amdgcn_sinf(rev);
    return make_float2(a.x * c + a.y * s, a.y * c - a.x * s);
}

// Shared pool: spectrum (skewed, 2*4*2112 = 16896 floats) is dead after
// extraction/refine; the synthesis tile (2144*8 = 17152 floats, t-major)
// reuses the same storage. Union size = 17152 floats = 68.6 KB.
#define SRE(w,a) POOL[(w) * 2112 + (a)]
#define SIM(w,a) POOL[8448 + (w) * 2112 + (a)]
#define TILE(tv,d8) POOL[(tv) * 8 + (d8)]

// ---------------------------------------------------------------------------
// Single fused kernel. 256 blocks x 256 threads. One wave = one packed
// signal-pair (FFT2048 = in-lane FFT32 x twiddle x cross-lane FFT64).
// Selection: both channels in one pass (half-wave per channel, sort-32 then
// top-16-truncated XOR merges). Rare fp64 refine. Synthesis into an LDS
// tile, then coalesced cooperative writeout (8 lines/store instead of 64).
// ---------------------------------------------------------------------------
__global__ __launch_bounds__(256) void fused_kernel(const float* __restrict__ x,
                                                    float* __restrict__ out) {
    __shared__ float POOL[17152];                  // 68.6 KB spectrum/tile union
    __shared__ int   coefK[8][KTOP];
    __shared__ float coefR[8][KTOP], coefI[8][KTOP];

    const int t    = threadIdx.x;
    const int wv   = t >> 6, lane = t & 63;
    // XCD swizzle: 8 blocks of one batch b land on one XCD.
    const int bid  = blockIdx.x;
    const int xcd  = bid & 7;
    const int idx  = bid >> 3;                     // 0..31
    const int b    = xcd * 4 + (idx >> 3);         // 0..31
    const int grp  = idx & 7;                      // d-group 0..7
    const int dp   = grp * 4 + wv;                 // d-pair 0..31
    const int d_base = grp * 8;

    const float2* xv = (const float2*)x;
    const size_t xbase = (size_t)b * TT * (DD / 2) + dp;

    // ---- load: v[i] = x[n = 64*br5(i) + lane] (bit-reversed for DIT-32) ----
    float2 v[32];
    #pragma unroll
    for (int i = 0; i < 32; ++i)
        v[i] = xv[xbase + (size_t)(64 * BR5[i] + lane) * (DD / 2)];

    // ---- in-lane FFT-32 (DIT, natural-order output, constant twiddles) ----
    #pragma unroll
    for (int s = 1; s <= 5; ++s) {
        const int m = 1 << s, half = m >> 1, stepw = 32 >> s;
        #pragma unroll
        for (int g = 0; g < 32; g += m) {
            #pragma unroll
            for (int j = 0; j < half; ++j) {
                const float c = C32T[j * stepw], sn = S32T[j * stepw];
                const int i0 = g + j, i1 = i0 + half;
                const float tr = c * v[i1].x + sn * v[i1].y;
                const float ti = c * v[i1].y - sn * v[i1].x;
                v[i1] = make_float2(v[i0].x - tr, v[i0].y - ti);
                v[i0] = make_float2(v[i0].x + tr, v[i0].y + ti);
            }
        }
    }

    // ---- twiddle: v[q] *= W2048^(lane*q) ----
    #pragma unroll
    for (int q = 1; q < 32; ++q) v[q] = ctw(v[q], (lane * q) & (TT - 1));

    // ---- cross-lane FFT-64: bit-reverse lanes, then 6 DIT shuffle stages ----
    {
        const int rl = br6(lane);
        #pragma unroll
        for (int q = 0; q < 32; ++q) {
            v[q].x = __shfl(v[q].x, rl, 64);
            v[q].y = __shfl(v[q].y, rl, 64);
        }
    }
    #pragma unroll
    for (int s = 1; s <= 6; ++s) {
        const int half = 1 << (s - 1);
        const float rev = (float)(lane & (half - 1)) / (float)(1 << s);
        const float wc  = __builtin_amdgcn_cosf(rev);
        const float wsn = __builtin_amdgcn_sinf(rev);
        const bool  hi  = (lane & half) != 0;
        #pragma unroll
        for (int q = 0; q < 32; ++q) {
            float2 pv;
            pv.x = __shfl_xor(v[q].x, half, 64);
            pv.y = __shfl_xor(v[q].y, half, 64);
            const float2 bsv = hi ? v[q] : pv;
            const float2 asv = hi ? pv : v[q];
            const float tr = wc * bsv.x + wsn * bsv.y;
            const float ti = wc * bsv.y - wsn * bsv.x;
            v[q] = hi ? make_float2(asv.x - tr, asv.y - ti)
                      : make_float2(asv.x + tr, asv.y + ti);
        }
    }
    // lane c holds X[32c + q] in v[q].

    // ---- dump spectrum (skewed a(k)=k+(k>>5), conflict-free). Own-wave
    // region only; same-wave DS ops are program-ordered -> no barrier needed.
    #pragma unroll
    for (int q = 0; q < 32; ++q) {
        const int a = 33 * lane + q;               // k=32*lane+q
        SRE(wv, a) = v[q].x;
        SIM(wv, a) = v[q].y;
    }

    // ======== selection: BOTH channels in one pass ========
    // lanes 0-31 -> sig0 (.x), lanes 32-63 -> sig1 (.y). Each half-wave:
    // 32 keys/lane covering bins 32*hl .. 32*hl+31.
    const int sig = lane >> 5, hl = lane & 31;
    unsigned A[32];
    #pragma unroll
    for (int q = 0; q < 32; ++q) {
        const int k = 32 * hl + q;
        unsigned kk = 0u;
        if (k != 0) {
            const int a1 = k + (k >> 5);
            const int pk = TT - k, a2 = pk + (pk >> 5);
            const float zr = SRE(wv, a1), zi = SIM(wv, a1);
            const float yr = SRE(wv, a2), yi = SIM(wv, a2);
            float cr, ci;
            if (sig == 0) { cr = 0.5f * (zr + yr); ci = 0.5f * (zi - yi); }
            else          { cr = 0.5f * (zi + yi); ci = 0.5f * (yr - zr); }
            const float mg = cr * cr + ci * ci;
            kk = (__float_as_uint(mg) & 0xFFFFF800u) | (unsigned)(2047 - k);
        }
        A[q] = kk;
    }

    // in-register bitonic sort-32, descending
    #pragma unroll
    for (int sz = 2; sz <= 32; sz <<= 1) {
        #pragma unroll
        for (int d = sz >> 1; d > 0; d >>= 1) {
            #pragma unroll
            for (int i2 = 0; i2 < 32; ++i2) {
                const int j2i = i2 ^ d;
                if (j2i > i2) {
                    const bool desc = ((i2 & sz) == 0);
                    const unsigned a = A[i2], b2 = A[j2i];
                    const unsigned mx = a > b2 ? a : b2, mn = a > b2 ? b2 : a;
                    A[i2] = desc ? mx : mn;  A[j2i] = desc ? mn : mx;
                }
            }
        }
    }
    // Keep only the sorted top-16 (top-16 of union of top-16s = global top-16).
    // 5 XOR-merge stages within each 32-lane half, 16-wide.
    #pragma unroll
    for (int off = 1; off <= 16; off <<= 1) {
        unsigned Bv[16];
        #pragma unroll
        for (int i2 = 0; i2 < 16; ++i2)
            Bv[i2] = (unsigned)__shfl_xor((int)A[i2], off, 64);
        #pragma unroll
        for (int i2 = 0; i2 < 16; ++i2) {
            const unsigned o = Bv[15 - i2];
            A[i2] = A[i2] > o ? A[i2] : o;         // top-16 multiset, bitonic
        }
        #pragma unroll
        for (int d = 8; d > 0; d >>= 1) {
            #pragma unroll
            for (int i2 = 0; i2 < 16; ++i2) {
                if ((i2 & d) == 0) {
                    const int j2i = i2 + d;
                    const unsigned a = A[i2], b2 = A[j2i];
                    A[i2] = a > b2 ? a : b2;  A[j2i] = a > b2 ? b2 : a;
                }
            }
        }
    }
    // every lane of half s: sorted top-16 of channel s

    const float m8f = __uint_as_float(A[7] & 0xFFFFF800u);
    unsigned bandmask = 0u;
    #pragma unroll
    for (int r = 0; r < 16; ++r) {
        const float mr = __uint_as_float(A[r] & 0xFFFFF800u);
        if (fabsf(mr - m8f) <= MARGIN * m8f) bandmask |= (1u << r);
    }
    const int flg = (bandmask != (1u << 7)) ? 1 : 0;   // uniform per half

    unsigned myk = 0u;                                 // cand hl (hl<16)
    #pragma unroll
    for (int i2 = 0; i2 < 16; ++i2) myk = (hl == i2) ? A[i2] : myk;
    const int kcand = 2047 - (int)(myk & 0x7FFu);
    const int s_local = 2 * wv + sig;                  // block-local signal 0..7

    if (!flg && hl < KTOP) {
        const int k = kcand, a1 = k + (k >> 5), pk = TT - k, a2 = pk + (pk >> 5);
        const float zr = SRE(wv, a1), zi = SIM(wv, a1);
        const float yr = SRE(wv, a2), yi = SIM(wv, a2);
        float cr, ci;
        if (sig == 0) { cr = 0.5f * (zr + yr); ci = 0.5f * (zi - yi); }
        else          { cr = 0.5f * (zi + yi); ci = 0.5f * (yr - zr); }
        coefK[s_local][hl] = k;
        coefR[s_local][hl] = cr * (2.0f / (float)TT);
        coefI[s_local][hl] = ci * (2.0f / (float)TT);
    }

    const int flg0 = __shfl(flg, 0, 64);
    const int flg1 = __shfl(flg, 32, 64);

    // ---- rare path: fp64 DFT of band members, exact re-rank + splice ----
    if (flg0 | flg1) {
        float2 sv[32];
        #pragma unroll
        for (int m = 0; m < 32; ++m)
            sv[m] = xv[xbase + (size_t)(lane + 64 * m) * (DD / 2)];
        const double thA = -2.0 * PI_D * (double)lane / 64.0;
        const double thB = -2.0 * PI_D * (double)lane / (double)TT;
        const double wac = cos(thA), was = sin(thA);
        const double wbc = cos(thB), wbs = sin(thB);

        for (int sg = 0; sg < 2; ++sg) {
            const int flg_s = (sg == 0) ? flg0 : flg1;
            if (!flg_s) continue;
            const unsigned bm = (unsigned)__shfl((int)bandmask, 32 * sg, 64);
            const int lo = (int)__builtin_ctz(bm);
            double myM = 0.0, myR = 0.0, myI = 0.0;
            for (int r = 0; r < 16; ++r) {
                if (!((bm >> r) & 1u)) continue;       // wave-uniform
                const int kr = __shfl(kcand, 32 * sg + r, 64);
                double ar = 0.0, ai = 0.0;
                for (int m = 0; m < 32; ++m) {
                    const int n  = lane + 64 * m;
                    const int mm = (n * kr) & (TT - 1);
                    const double qc  = __shfl(wac, mm >> 5, 64);
                    const double qs  = __shfl(was, mm >> 5, 64);
                    const double rc2 = __shfl(wbc, mm & 31, 64);
                    const double rs2 = __shfl(wbs, mm & 31, 64);
                    const double wr = qc * rc2 - qs * rs2;
                    const double wi = qc * rs2 + qs * rc2;
                    const double xs = (sg == 0) ? (double)sv[m].x : (double)sv[m].y;
                    ar = fma(xs, wr, ar);
                    ai = fma(xs, wi, ai);
                }
                #pragma unroll
                for (int off = 32; off; off >>= 1) {
                    ar += __shfl_xor(ar, off, 64);
                    ai += __shfl_xor(ai, off, 64);
                }
                if (lane == 32 * sg + r) { myM = ar * ar + ai * ai; myR = ar; myI = ai; }
            }
            // rank on ALL lanes (shuffles fully active), write on half sg
            const int h16 = hl & 15;
            const double selfM = __shfl(myM, 32 * sg + h16, 64);
            const int    selfK = __shfl(kcand, 32 * sg + h16, 64);
            int rb = 0;
            for (int r2 = 0; r2 < 16; ++r2) {
                if (!((bm >> r2) & 1u)) continue;
                const double om = __shfl(myM, 32 * sg + r2, 64);
                const int    ok = __shfl(kcand, 32 * sg + r2, 64);
                if (r2 != h16 && (om > selfM || (om == selfM && ok < selfK))) ++rb;
            }
            const int isband = (int)((bm >> h16) & 1u);
            const int rank = isband ? (lo + rb) : h16;
            if (sig == sg && hl < 16 && rank < KTOP) {
                coefK[s_local][rank] = kcand;
                if (isband) {
                    coefR[s_local][rank] = (float)(myR * (2.0 / (double)TT));
                    coefI[s_local][rank] = (float)(myI * (2.0 / (double)TT));
                } else {
                    const int k = kcand, a1 = k + (k >> 5), pk = TT - k, a2 = pk + (pk >> 5);
                    const float zr = SRE(wv, a1), zi = SIM(wv, a1);
                    const float yr = SRE(wv, a2), yi = SIM(wv, a2);
                    float cr, ci;
                    if (sg == 0) { cr = 0.5f * (zr + yr); ci = 0.5f * (zi - yi); }
                    else          { cr = 0.5f * (zi + yi); ci = 0.5f * (yr - zr); }
                    coefR[s_local][rank] = cr * (2.0f / (float)TT);
                    coefI[s_local][rank] = ci * (2.0f / (float)TT);
                }
            }
        }
    }
    __syncthreads();   // coefs ready; spectrum dead -> pool becomes the tile

    // ======== synthesis into the LDS tile (phasor rotation) ========
    // thread -> (d8 = t&7, tq = t>>3); tile write addr = tv*8+d8 = t+256m
    // -> bank = lane&31 (2-way across half-waves = free).
    const int d8 = t & 7, tq = t >> 3;
    int   kc[KTOP];
    float fr[KTOP], fi[KTOP], pc[KTOP], ps[KTOP], rc[KTOP], rs[KTOP];
    #pragma unroll
    for (int p = 0; p < KTOP; ++p) {
        kc[p] = coefK[d8][p];
        fr[p] = coefR[d8][p];
        fi[p] = coefI[d8][p];
        const int j0 = (kc[p] * tq) & (TT - 1);
        const float rv0 = (float)j0 * (1.0f / 2048.0f);
        pc[p] = __builtin_amdgcn_cosf(rv0);
        ps[p] = __builtin_amdgcn_sinf(rv0);
        const int jr = (kc[p] * 32) & (TT - 1);
        const float rvr = (float)jr * (1.0f / 2048.0f);
        rc[p] = __builtin_amdgcn_cosf(rvr);
        rs[p] = __builtin_amdgcn_sinf(rvr);
    }
    #pragma unroll 4
    for (int m = 0; m < 67; ++m) {                 // 67*32 = 2144 = TP exactly
        const int tv = tq + 32 * m;
        float acc = 0.0f;
        #pragma unroll
        for (int p = 0; p < KTOP; ++p) acc += fr[p] * pc[p] - fi[p] * ps[p];
        TILE(tv, d8) = acc;
        #pragma unroll
        for (int p = 0; p < KTOP; ++p) {
            const float nc = pc[p] * rc[p] - ps[p] * rs[p];
            const float ns = pc[p] * rs[p] + ps[p] * rc[p];
            pc[p] = nc; ps[p] = ns;
        }
    }
    __syncthreads();   // all 8 channels of the tile complete

    // ======== coalesced writeout: d8-fastest lanes, 8 lines/store ========
    float* ob = out + (size_t)b * TP * DD + d_base;
    for (int it = 0; it < 67; ++it) {
        const int f  = it * 256 + t;               // 0..17151, linear LDS read
        const int dd = f & 7, tv = f >> 3;
        ob[(size_t)tv * DD + dd] = POOL[f];
    }
}

extern "C" void kernel_launch(void* const* d_in, const int* in_sizes, int n_in,
                              void* d_out, int out_size, void* d_ws, size_t ws_size,
                              hipStream_t stream) {
    const float* x = (const float*)d_in[0];
    float* out = (float*)d_out;
    (void)d_ws; (void)ws_size; (void)in_sizes; (void)n_in; (void)out_size;

    fused_kernel<<<BB * 8, 256, 0, stream>>>(x, out);
}